// Round 6
// baseline (250.951 us; speedup 1.0000x reference)
//
#include <hip/hip_runtime.h>
#include <hip/hip_bf16.h>
#include <cstdint>

// ---------------------------------------------------------------------------
// SingleDeformConv on MI355X (gfx950)
// data (8,64,128,128) f32; w (64,64,3,3); b (64); w_off (18,64,3,3); b_off(18);
// w_mod (9,64,3,3); b_mod (9).  out = relu(deform_conv(...)) (8,64,128,128) f32
//
// R5 -> R6: fusion REVERTED (8-way LDS conflicts + serialization regressed).
// deform_main rebuilt: lane (r,q) gathers channels q*8..q*8+7 of position r —
// the exact MFMA B-fragment layout — so blended values feed MFMA directly
// from registers. No samp LDS tile, no pack-perm, ZERO k-loop barriers.
// Corner-load totals unchanged; A-frags read per-wave from L1.
// ---------------------------------------------------------------------------

typedef __attribute__((ext_vector_type(8))) short short8;
typedef __attribute__((ext_vector_type(4))) float floatx4;
typedef __attribute__((ext_vector_type(2))) float floatx2;

__device__ __forceinline__ unsigned short f2bf(float x) {
    unsigned int u = __float_as_uint(x);
    u += 0x7fffu + ((u >> 16) & 1u);           // round-to-nearest-even
    return (unsigned short)(u >> 16);
}
// pack two floats -> bf16x2 dword (RNE)
__device__ __forceinline__ unsigned int pack2bf(float lo, float hi) {
    unsigned int ul = __float_as_uint(lo); ul += 0x7fffu + ((ul >> 16) & 1u);
    unsigned int uh = __float_as_uint(hi); uh += 0x7fffu + ((uh >> 16) & 1u);
    return __builtin_amdgcn_perm(uh, ul, 0x07060302u);
}
// unpack bf16x2 dword -> float2 (lo, hi)
__device__ __forceinline__ floatx2 up2(unsigned int u) {
    floatx2 r;
    r.x = __uint_as_float(u << 16);
    r.y = __uint_as_float(u & 0xffff0000u);
    return r;
}
// blend 2 channels (bf16x2 dwords from 4 corners) -> packed bf16x2 (RNE)
__device__ __forceinline__ unsigned int blend2pk(unsigned int a, unsigned int b,
                                                 unsigned int c, unsigned int d,
                                                 float4 fw) {
    floatx2 s = up2(a) * fw.x;
    s += up2(b) * fw.y;
    s += up2(c) * fw.z;
    s += up2(d) * fw.w;
    __hip_bfloat162 h = __float22bfloat162_rn(make_float2(s.x, s.y));
    return *(unsigned int*)&h;
}

// Workspace layout (bytes)
#define OFF_DATAT 0u               // [8][16384][64] bf16  = 16777216 B
#define OFF_OFFP  16777216u        // [8][9][3][16384] f32 = 14155776 B (dy,dx,mask)
#define OFF_WM    30932992u        // [64][576] bf16       = 73728 B
#define OFF_W27   31006720u        // [32][576] bf16       = 36864 B
#define OFF_B27   31043584u        // [32] f32             = 128 B
// total 31043712 B

// ---------------------------------------------------------------------------
// Kernel 1: prep = NCHW f32 -> NHWC bf16 transpose (blocks 0..2047)
//           + weight packing / bias27 (blocks 2048..2263)
// ---------------------------------------------------------------------------
__global__ __launch_bounds__(256) void prep_k(const float* __restrict__ x,
                                              unsigned short* __restrict__ xt,
                                              const float* __restrict__ w,
                                              const float* __restrict__ w_off,
                                              const float* __restrict__ w_mod,
                                              const float* __restrict__ b_off,
                                              const float* __restrict__ b_mod,
                                              unsigned short* __restrict__ wpackM,
                                              unsigned short* __restrict__ wpack27,
                                              float* __restrict__ bias27) {
    __shared__ float tile[64][65];
    int blk = blockIdx.x;
    if (blk < 2048) {                              // ---- transpose ----
        int b    = blk >> 8;
        int pos0 = (blk & 255) << 6;
        int lane = threadIdx.x & 63;
        int g    = threadIdx.x >> 6;
        for (int c = g; c < 64; c += 4)
            tile[c][lane] = x[(((b << 6) + c) << 14) + pos0 + lane];
        __syncthreads();
        int c2 = lane & 31;
        for (int i = g; i < 32; i += 4) {
            int pr = (i << 1) + (lane >> 5);
            unsigned int d = pack2bf(tile[c2 << 1][pr], tile[(c2 << 1) + 1][pr]);
            *(unsigned int*)&xt[((size_t)((b << 14) + pos0 + pr) << 6) + (c2 << 1)] = d;
        }
        return;
    }
    // ---- weight packing ----
    int t = (blk - 2048) * 256 + threadIdx.x;
    if (t < 64 * 576) {
        int o = t / 576, kk = t % 576;
        int k = kk >> 6, c = kk & 63;
        wpackM[t] = f2bf(w[(o * 64 + c) * 9 + k]);
        return;
    }
    t -= 64 * 576;
    if (t < 32 * 576) {
        int o = t / 576, kk = t % 576;
        int k = kk >> 6, c = kk & 63;
        float v = 0.f;
        if (o < 18)      v = w_off[(o * 64 + c) * 9 + k];
        else if (o < 27) v = w_mod[((o - 18) * 64 + c) * 9 + k];
        wpack27[t] = f2bf(v);
        if (kk == 0) bias27[o] = (o < 18) ? b_off[o] : (o < 27 ? b_mod[o - 18] : 0.f);
    }
}

// ---------------------------------------------------------------------------
// Kernel 2: offset/mask conv (27 ch, padded to 32) — R4 version (proven ~fast).
// Block: 256 thr, 2x64 patch, halo [4][66][72] (38 KB), b128 staging.
// ---------------------------------------------------------------------------
__global__ __launch_bounds__(256) void conv27_k(const unsigned short* __restrict__ xt,
                                                const unsigned short* __restrict__ wpack27,
                                                const float* __restrict__ bias27,
                                                float* __restrict__ offP) {
    __shared__ unsigned short tile[4][66][72];
    int blk   = blockIdx.x;                         // 1024 = 8 b * 128 patches
    int b     = blk >> 7;
    int patch = blk & 127;
    int m     = patch >> 1;
    int h     = patch & 1;
    int tid   = threadIdx.x;
    int lane  = tid & 63, wv = tid >> 6;
    int r = lane & 15, q = lane >> 4;

    const unsigned short* xb = xt + ((size_t)b << 20);

    {
        int g = tid >> 3, j = tid & 7;
        #pragma unroll
        for (int rr = 0; rr < 4; ++rr) {
            int sy = (m << 1) + rr - 1;
            #pragma unroll
            for (int ci = 0; ci < 3; ++ci) {
                int col = g + (ci << 5);
                if (col < 66) {
                    int sx = (h << 6) + col - 1;
                    uint4 v = {0u, 0u, 0u, 0u};
                    if (sy >= 0 && sy < 128 && sx >= 0 && sx < 128)
                        v = *(const uint4*)&xb[(size_t)(((sy << 7) + sx) << 6) + (j << 3)];
                    *(uint4*)&tile[rr][col][j << 3] = v;
                }
            }
        }
    }
    __syncthreads();

    floatx4 acc[4] = {};
    #pragma unroll
    for (int k = 0; k < 9; ++k) {
        int ki = k / 3, kj = k % 3;
        #pragma unroll
        for (int ch = 0; ch < 2; ++ch) {
            short8 a0 = *(const short8*)&wpack27[(r)      * 576 + (k << 6) + (ch << 5) + (q << 3)];
            short8 a1 = *(const short8*)&wpack27[(16 + r) * 576 + (k << 6) + (ch << 5) + (q << 3)];
            #pragma unroll
            for (int tr = 0; tr < 2; ++tr) {
                short8 bfrag = *(const short8*)&tile[tr + ki][(wv << 4) + r + kj][(ch << 5) + (q << 3)];
                acc[0 + tr] = __builtin_amdgcn_mfma_f32_16x16x32_bf16(a0, bfrag, acc[0 + tr], 0, 0, 0);
                acc[2 + tr] = __builtin_amdgcn_mfma_f32_16x16x32_bf16(a1, bfrag, acc[2 + tr], 0, 0, 0);
            }
        }
    }

    #pragma unroll
    for (int s = 0; s < 2; ++s) {
        #pragma unroll
        for (int tr = 0; tr < 2; ++tr) {
            #pragma unroll
            for (int reg = 0; reg < 4; ++reg) {
                int oc = (s << 4) + (q << 2) + reg;
                if (oc >= 27) continue;
                int pos = (((m << 1) + tr) << 7) + (h << 6) + (wv << 4) + r;
                float v = acc[(s << 1) + tr][reg] + bias27[oc];
                int kk, comp;
                if (oc < 18) { kk = oc >> 1; comp = oc & 1; }
                else         { kk = oc - 18; comp = 2; v = 2.f / (1.f + __expf(-v)); }
                offP[(size_t)(((b * 9 + kk) * 3 + comp) << 14) + pos] = v;
            }
        }
    }
}

// ---------------------------------------------------------------------------
// Kernel 3: main deformable conv — register-direct B-fragments.
// Block: 256 thr (4 waves), 64 positions; wave wv owns positions wv*16..+16,
// ALL 64 oc. Lane (r,q) gathers channels q*8..q*8+7 of position r for both
// 32-ch K-chunks — exactly the MFMA B-fragment layout. No samp LDS, no
// k-loop barriers. A-frags (4 strips x 2 ch per tap) read from L1.
// LDS: pOff/pW only (18.4 KB).
// ---------------------------------------------------------------------------
__global__ __launch_bounds__(256) void deform_main_k(const unsigned short* __restrict__ xt,
                                                     const unsigned short* __restrict__ wpackM,
                                                     const float* __restrict__ offP,
                                                     const float* __restrict__ bias,
                                                     float* __restrict__ out) {
    __shared__ int4   pOff[576];                    // 9216 B  corner byte-offsets
    __shared__ float4 pW[576];                      // 9216 B  mask-folded weights
    int blk  = blockIdx.x;                          // 2048 = 8 b * 256
    int b    = blk >> 8;
    int pos0 = (blk & 255) << 6;
    int tid  = threadIdx.x;
    int lane = tid & 63, wv = tid >> 6;
    int r = lane & 15, q = lane >> 4;

    // ---- phase 0: params, one thread per (tap,pos) entry ----
    for (int e = tid; e < 576; e += 256) {
        int k = e >> 6, p = e & 63;
        int pos = pos0 + p;
        const float* offk = offP + ((size_t)((b * 9 + k) * 3) << 14);
        float dy = offk[pos];
        float dx = offk[16384 + pos];
        float m  = offk[32768 + pos];
        float py = (float)(pos >> 7) + (float)(k / 3 - 1) + dy;
        float px = (float)(pos & 127) + (float)(k % 3 - 1) + dx;
        float y0f = floorf(py), x0f = floorf(px);
        int y0 = (int)y0f, x0 = (int)x0f;
        float wy1 = py - y0f, wx1 = px - x0f;
        float wy0 = 1.f - wy1, wx0 = 1.f - wx1;
        bool vy0 = (y0 >= 0) && (y0 < 128);
        bool vy1 = (y0 >= -1) && (y0 < 127);
        bool vx0 = (x0 >= 0) && (x0 < 128);
        bool vx1 = (x0 >= -1) && (x0 < 127);
        float w00 = (vy0 && vx0) ? m * wy0 * wx0 : 0.f;
        float w01 = (vy0 && vx1) ? m * wy0 * wx1 : 0.f;
        float w10 = (vy1 && vx0) ? m * wy1 * wx0 : 0.f;
        float w11 = (vy1 && vx1) ? m * wy1 * wx1 : 0.f;
        int y0c = min(max(y0, 0), 127), y1c = min(max(y0 + 1, 0), 127);
        int x0c = min(max(x0, 0), 127), x1c = min(max(x0 + 1, 0), 127);
        pOff[e] = make_int4(((y0c << 7) + x0c) << 7, ((y0c << 7) + x1c) << 7,
                            ((y1c << 7) + x0c) << 7, ((y1c << 7) + x1c) << 7);
        pW[e] = make_float4(w00, w01, w10, w11);
    }
    __syncthreads();                                // params ready — last barrier

    floatx4 acc[4] = {};                            // 4 oc strips x (16 pos this wave)
    const char* xq = (const char*)(xt + ((size_t)b << 20)) + (q << 4);
    const unsigned short* wbase = wpackM + r * 576 + (q << 3);

    // params software-prefetch across taps (ds latency off the critical path)
    int4   io = pOff[(wv << 4) + r];
    float4 fw = pW[(wv << 4) + r];

    for (int k = 0; k < 9; ++k) {
        int4 ioN; float4 fwN;
        if (k < 8) {
            int eN = ((k + 1) << 6) + (wv << 4) + r;
            ioN = pOff[eN];
            fwN = pW[eN];
        }
        short8 bfr[2];
        #pragma unroll
        for (int ch = 0; ch < 2; ++ch) {
            const char* base = xq + (ch << 6);
            uint4 u00 = *(const uint4*)(base + io.x);
            uint4 u01 = *(const uint4*)(base + io.y);
            uint4 u10 = *(const uint4*)(base + io.z);
            uint4 u11 = *(const uint4*)(base + io.w);
            uint4 o4;
            o4.x = blend2pk(u00.x, u01.x, u10.x, u11.x, fw);
            o4.y = blend2pk(u00.y, u01.y, u10.y, u11.y, fw);
            o4.z = blend2pk(u00.z, u01.z, u10.z, u11.z, fw);
            o4.w = blend2pk(u00.w, u01.w, u10.w, u11.w, fw);
            union { uint4 u; short8 s; } cv; cv.u = o4;
            bfr[ch] = cv.s;
        }
        #pragma unroll
        for (int st = 0; st < 4; ++st) {
            #pragma unroll
            for (int ch = 0; ch < 2; ++ch) {
                short8 a = *(const short8*)&wbase[(st << 4) * 576 + (k << 6) + (ch << 5)];
                acc[st] = __builtin_amdgcn_mfma_f32_16x16x32_bf16(a, bfr[ch], acc[st], 0, 0, 0);
            }
        }
        io = ioN; fw = fwN;
    }

    #pragma unroll
    for (int st = 0; st < 4; ++st) {
        #pragma unroll
        for (int reg = 0; reg < 4; ++reg) {
            int oc  = (st << 4) + (q << 2) + reg;
            int pos = pos0 + (wv << 4) + r;
            float v = acc[st][reg] + bias[oc];
            out[(size_t)(((b << 6) + oc) << 14) + pos] = fmaxf(v, 0.f);
        }
    }
}

// ---------------------------------------------------------------------------
extern "C" void kernel_launch(void* const* d_in, const int* in_sizes, int n_in,
                              void* d_out, int out_size, void* d_ws, size_t ws_size,
                              hipStream_t stream) {
    const float* data  = (const float*)d_in[0];
    const float* w     = (const float*)d_in[1];
    const float* bias  = (const float*)d_in[2];
    const float* w_off = (const float*)d_in[3];
    const float* b_off = (const float*)d_in[4];
    const float* w_mod = (const float*)d_in[5];
    const float* b_mod = (const float*)d_in[6];
    float* out = (float*)d_out;

    char* ws = (char*)d_ws;
    unsigned short* dataT   = (unsigned short*)(ws + OFF_DATAT);
    float*          offP    = (float*)(ws + OFF_OFFP);
    unsigned short* wpackM  = (unsigned short*)(ws + OFF_WM);
    unsigned short* wpack27 = (unsigned short*)(ws + OFF_W27);
    float*          bias27  = (float*)(ws + OFF_B27);

    prep_k<<<2264, 256, 0, stream>>>(data, dataT, w, w_off, w_mod,
                                     b_off, b_mod, wpackM, wpack27, bias27);
    conv27_k<<<1024, 256, 0, stream>>>(dataT, wpack27, bias27, offP);
    deform_main_k<<<2048, 256, 0, stream>>>(dataT, wpackM, offP, bias, out);
}

// Round 7
// 161.621 us; speedup vs baseline: 1.5527x; 1.5527x over previous
//
#include <hip/hip_runtime.h>
#include <hip/hip_bf16.h>
#include <cstdint>

// ---------------------------------------------------------------------------
// SingleDeformConv on MI355X (gfx950)
// data (8,64,128,128) f32; w (64,64,3,3); b (64); w_off (18,64,3,3); b_off(18);
// w_mod (9,64,3,3); b_mod (9).  out = relu(deform_conv(...)) (8,64,128,128) f32
//
// R6 -> R7: register-direct variant REVERTED (latency-bound, VALUBusy 16%).
// Back to R4's pipelined deform_main (proven 51 us), plus:
//  * params compressed to 24 B/entry (ushort4 corner pos-index + float4 wgt)
//    -> LDS 32.2 KB -> 5 blocks/CU, __launch_bounds__(256,5)
//  * next-tap params held in registers so corner globals issue immediately;
//    params for tap k+2 read after blendStore(k+1)
// ---------------------------------------------------------------------------

typedef __attribute__((ext_vector_type(8))) short short8;
typedef __attribute__((ext_vector_type(4))) float floatx4;
typedef __attribute__((ext_vector_type(2))) float floatx2;

__device__ __forceinline__ unsigned short f2bf(float x) {
    unsigned int u = __float_as_uint(x);
    u += 0x7fffu + ((u >> 16) & 1u);           // round-to-nearest-even
    return (unsigned short)(u >> 16);
}
// pack two floats -> bf16x2 dword (RNE)
__device__ __forceinline__ unsigned int pack2bf(float lo, float hi) {
    unsigned int ul = __float_as_uint(lo); ul += 0x7fffu + ((ul >> 16) & 1u);
    unsigned int uh = __float_as_uint(hi); uh += 0x7fffu + ((uh >> 16) & 1u);
    return __builtin_amdgcn_perm(uh, ul, 0x07060302u);
}
// unpack bf16x2 dword -> float2 (lo, hi)
__device__ __forceinline__ floatx2 up2(unsigned int u) {
    floatx2 r;
    r.x = __uint_as_float(u << 16);
    r.y = __uint_as_float(u & 0xffff0000u);
    return r;
}
// blend 2 channels (bf16x2 dwords from 4 corners) -> packed bf16x2 (RNE)
__device__ __forceinline__ unsigned int blend2pk(unsigned int a, unsigned int b,
                                                 unsigned int c, unsigned int d,
                                                 float4 fw) {
    floatx2 s = up2(a) * fw.x;
    s += up2(b) * fw.y;
    s += up2(c) * fw.z;
    s += up2(d) * fw.w;
    __hip_bfloat162 h = __float22bfloat162_rn(make_float2(s.x, s.y));
    return *(unsigned int*)&h;
}

// Workspace layout (bytes)
#define OFF_DATAT 0u               // [8][16384][64] bf16  = 16777216 B
#define OFF_OFFP  16777216u        // [8][9][3][16384] f32 = 14155776 B (dy,dx,mask)
#define OFF_WM    30932992u        // [64][576] bf16       = 73728 B
#define OFF_W27   31006720u        // [32][576] bf16       = 36864 B
#define OFF_B27   31043584u        // [32] f32             = 128 B
// total 31043712 B

// ---------------------------------------------------------------------------
// Kernel 1: prep = NCHW f32 -> NHWC bf16 transpose (blocks 0..2047)
//           + weight packing / bias27 (blocks 2048..2263)
// ---------------------------------------------------------------------------
__global__ __launch_bounds__(256) void prep_k(const float* __restrict__ x,
                                              unsigned short* __restrict__ xt,
                                              const float* __restrict__ w,
                                              const float* __restrict__ w_off,
                                              const float* __restrict__ w_mod,
                                              const float* __restrict__ b_off,
                                              const float* __restrict__ b_mod,
                                              unsigned short* __restrict__ wpackM,
                                              unsigned short* __restrict__ wpack27,
                                              float* __restrict__ bias27) {
    __shared__ float tile[64][65];
    int blk = blockIdx.x;
    if (blk < 2048) {                              // ---- transpose ----
        int b    = blk >> 8;
        int pos0 = (blk & 255) << 6;
        int lane = threadIdx.x & 63;
        int g    = threadIdx.x >> 6;
        for (int c = g; c < 64; c += 4)
            tile[c][lane] = x[(((b << 6) + c) << 14) + pos0 + lane];
        __syncthreads();
        int c2 = lane & 31;
        for (int i = g; i < 32; i += 4) {
            int pr = (i << 1) + (lane >> 5);
            unsigned int d = pack2bf(tile[c2 << 1][pr], tile[(c2 << 1) + 1][pr]);
            *(unsigned int*)&xt[((size_t)((b << 14) + pos0 + pr) << 6) + (c2 << 1)] = d;
        }
        return;
    }
    // ---- weight packing ----
    int t = (blk - 2048) * 256 + threadIdx.x;
    if (t < 64 * 576) {
        int o = t / 576, kk = t % 576;
        int k = kk >> 6, c = kk & 63;
        wpackM[t] = f2bf(w[(o * 64 + c) * 9 + k]);
        return;
    }
    t -= 64 * 576;
    if (t < 32 * 576) {
        int o = t / 576, kk = t % 576;
        int k = kk >> 6, c = kk & 63;
        float v = 0.f;
        if (o < 18)      v = w_off[(o * 64 + c) * 9 + k];
        else if (o < 27) v = w_mod[((o - 18) * 64 + c) * 9 + k];
        wpack27[t] = f2bf(v);
        if (kk == 0) bias27[o] = (o < 18) ? b_off[o] : (o < 27 ? b_mod[o - 18] : 0.f);
    }
}

// ---------------------------------------------------------------------------
// Kernel 2: offset/mask conv (27 ch, padded to 32) — implicit GEMM, bf16 MFMA.
// Block: 256 thr, 2x64 patch, halo [4][66][72] (38 KB), b128 staging.
// ---------------------------------------------------------------------------
__global__ __launch_bounds__(256) void conv27_k(const unsigned short* __restrict__ xt,
                                                const unsigned short* __restrict__ wpack27,
                                                const float* __restrict__ bias27,
                                                float* __restrict__ offP) {
    __shared__ unsigned short tile[4][66][72];
    int blk   = blockIdx.x;                         // 1024 = 8 b * 128 patches
    int b     = blk >> 7;
    int patch = blk & 127;
    int m     = patch >> 1;
    int h     = patch & 1;
    int tid   = threadIdx.x;
    int lane  = tid & 63, wv = tid >> 6;
    int r = lane & 15, q = lane >> 4;

    const unsigned short* xb = xt + ((size_t)b << 20);

    {
        int g = tid >> 3, j = tid & 7;
        #pragma unroll
        for (int rr = 0; rr < 4; ++rr) {
            int sy = (m << 1) + rr - 1;
            #pragma unroll
            for (int ci = 0; ci < 3; ++ci) {
                int col = g + (ci << 5);
                if (col < 66) {
                    int sx = (h << 6) + col - 1;
                    uint4 v = {0u, 0u, 0u, 0u};
                    if (sy >= 0 && sy < 128 && sx >= 0 && sx < 128)
                        v = *(const uint4*)&xb[(size_t)(((sy << 7) + sx) << 6) + (j << 3)];
                    *(uint4*)&tile[rr][col][j << 3] = v;
                }
            }
        }
    }
    __syncthreads();

    floatx4 acc[4] = {};
    #pragma unroll
    for (int k = 0; k < 9; ++k) {
        int ki = k / 3, kj = k % 3;
        #pragma unroll
        for (int ch = 0; ch < 2; ++ch) {
            short8 a0 = *(const short8*)&wpack27[(r)      * 576 + (k << 6) + (ch << 5) + (q << 3)];
            short8 a1 = *(const short8*)&wpack27[(16 + r) * 576 + (k << 6) + (ch << 5) + (q << 3)];
            #pragma unroll
            for (int tr = 0; tr < 2; ++tr) {
                short8 bfrag = *(const short8*)&tile[tr + ki][(wv << 4) + r + kj][(ch << 5) + (q << 3)];
                acc[0 + tr] = __builtin_amdgcn_mfma_f32_16x16x32_bf16(a0, bfrag, acc[0 + tr], 0, 0, 0);
                acc[2 + tr] = __builtin_amdgcn_mfma_f32_16x16x32_bf16(a1, bfrag, acc[2 + tr], 0, 0, 0);
            }
        }
    }

    #pragma unroll
    for (int s = 0; s < 2; ++s) {
        #pragma unroll
        for (int tr = 0; tr < 2; ++tr) {
            #pragma unroll
            for (int reg = 0; reg < 4; ++reg) {
                int oc = (s << 4) + (q << 2) + reg;
                if (oc >= 27) continue;
                int pos = (((m << 1) + tr) << 7) + (h << 6) + (wv << 4) + r;
                float v = acc[(s << 1) + tr][reg] + bias27[oc];
                int kk, comp;
                if (oc < 18) { kk = oc >> 1; comp = oc & 1; }
                else         { kk = oc - 18; comp = 2; v = 2.f / (1.f + __expf(-v)); }
                offP[(size_t)(((b * 9 + kk) * 3 + comp) << 14) + pos] = v;
            }
        }
    }
}

// ---------------------------------------------------------------------------
// Kernel 3: main deformable conv — R4 pipelined structure.
// Block: 256 thr (4 waves), 64 positions. Phase 0: 576 (tap,pos) params
// (ushort4 corner pos-indices + float4 mask-folded weights, 24 B/entry).
// K-loop: corner b128 loads for tap k+1 issued from register-held params
// before the barrier; MFMA(k) from samp[k&1]; blend(k+1) -> samp[(k+1)&1];
// params for k+2 read after. LDS 32.2 KB -> 5 blocks/CU.
// ---------------------------------------------------------------------------
__global__ __launch_bounds__(256, 5) void deform_main_k(const unsigned short* __restrict__ xt,
                                                        const unsigned short* __restrict__ wpackM,
                                                        const float* __restrict__ offP,
                                                        const float* __restrict__ bias,
                                                        float* __restrict__ out) {
    __shared__ ushort4 pOff[576];                   // 4608 B  corner pos-indices
    __shared__ float4  pW[576];                     // 9216 B  mask-folded weights
    __shared__ unsigned short samp[2][64][72];      // 18432 B B-tile (double buf)
    int blk  = blockIdx.x;                          // 2048 = 8 b * 256
    int b    = blk >> 8;
    int pos0 = (blk & 255) << 6;
    int tid  = threadIdx.x;
    int lane = tid & 63, wv = tid >> 6;
    int r = lane & 15, q = lane >> 4;
    int pg = lane >> 3;                             // position subgroup 0..7
    int j8 = lane & 7;                              // channel chunk (8 bf16 = 16B)

    const char* xbb = (const char*)(xt + ((size_t)b << 20));

    // ---- phase 0: params, one thread per (tap,pos) entry ----
    for (int e = tid; e < 576; e += 256) {
        int k = e >> 6, p = e & 63;
        int pos = pos0 + p;
        const float* offk = offP + ((size_t)((b * 9 + k) * 3) << 14);
        float dy = offk[pos];
        float dx = offk[16384 + pos];
        float m  = offk[32768 + pos];
        float py = (float)(pos >> 7) + (float)(k / 3 - 1) + dy;
        float px = (float)(pos & 127) + (float)(k % 3 - 1) + dx;
        float y0f = floorf(py), x0f = floorf(px);
        int y0 = (int)y0f, x0 = (int)x0f;
        float wy1 = py - y0f, wx1 = px - x0f;
        float wy0 = 1.f - wy1, wx0 = 1.f - wx1;
        bool vy0 = (y0 >= 0) && (y0 < 128);
        bool vy1 = (y0 >= -1) && (y0 < 127);
        bool vx0 = (x0 >= 0) && (x0 < 128);
        bool vx1 = (x0 >= -1) && (x0 < 127);
        float w00 = (vy0 && vx0) ? m * wy0 * wx0 : 0.f;
        float w01 = (vy0 && vx1) ? m * wy0 * wx1 : 0.f;
        float w10 = (vy1 && vx0) ? m * wy1 * wx0 : 0.f;
        float w11 = (vy1 && vx1) ? m * wy1 * wx1 : 0.f;
        int y0c = min(max(y0, 0), 127), y1c = min(max(y0 + 1, 0), 127);
        int x0c = min(max(x0, 0), 127), x1c = min(max(x0 + 1, 0), 127);
        ushort4 io;
        io.x = (unsigned short)((y0c << 7) + x0c);
        io.y = (unsigned short)((y0c << 7) + x1c);
        io.z = (unsigned short)((y1c << 7) + x0c);
        io.w = (unsigned short)((y1c << 7) + x1c);
        pOff[e] = io;
        pW[e] = make_float4(w00, w01, w10, w11);
    }
    __syncthreads();                                // pOff/pW ready

    floatx4 acc[4] = {};
    const char* xp = xbb + (j8 << 4);               // per-lane channel-chunk base
    const unsigned short* wrow = wpackM + ((wv << 4) + r) * 576 + (q << 3);

    uint4   c00[2], c01[2], c10[2], c11[2];         // prefetched corners
    ushort4 pio[2];                                 // params for next issue
    float4  pcw[2];
    float4  cw[2];                                  // weights matching corners
    short8  afC[2], afN[2];                         // A-frags, current / next

    auto readParams = [&](int k) {
        #pragma unroll
        for (int i = 0; i < 2; ++i) {
            int e  = (k << 6) + (wv << 4) + (i << 3) + pg;
            pio[i] = pOff[e];
            pcw[i] = pW[e];
        }
    };
    auto issue = [&]() {                            // fire globals from registers
        #pragma unroll
        for (int i = 0; i < 2; ++i) {
            cw[i]  = pcw[i];
            c00[i] = *(const uint4*)(xp + ((int)pio[i].x << 7));
            c01[i] = *(const uint4*)(xp + ((int)pio[i].y << 7));
            c10[i] = *(const uint4*)(xp + ((int)pio[i].z << 7));
            c11[i] = *(const uint4*)(xp + ((int)pio[i].w << 7));
        }
    };
    auto blendStore = [&](int buf) {
        #pragma unroll
        for (int i = 0; i < 2; ++i) {
            int p = (wv << 4) + (i << 3) + pg;
            uint4 o4;
            o4.x = blend2pk(c00[i].x, c01[i].x, c10[i].x, c11[i].x, cw[i]);
            o4.y = blend2pk(c00[i].y, c01[i].y, c10[i].y, c11[i].y, cw[i]);
            o4.z = blend2pk(c00[i].z, c01[i].z, c10[i].z, c11[i].z, cw[i]);
            o4.w = blend2pk(c00[i].w, c01[i].w, c10[i].w, c11[i].w, cw[i]);
            *(uint4*)&samp[buf][p][j8 << 3] = o4;
        }
    };

    // prologue: tap 0 through the pipe; params for tap 1 staged in registers
    readParams(0);
    issue();
    afC[0] = *(const short8*)&wrow[0];
    afC[1] = *(const short8*)&wrow[32];
    blendStore(0);
    readParams(1);

    for (int k = 0; k < 9; ++k) {
        if (k < 8) {
            issue();                                // tap k+1 globals in flight
            afN[0] = *(const short8*)&wrow[((k + 1) << 6)];
            afN[1] = *(const short8*)&wrow[((k + 1) << 6) + 32];
        }
        __syncthreads();                            // samp[k&1] complete block-wide
        #pragma unroll
        for (int ch = 0; ch < 2; ++ch) {
            #pragma unroll
            for (int nt = 0; nt < 4; ++nt) {
                short8 bfrag = *(const short8*)&samp[k & 1][(nt << 4) + r][(ch << 5) + (q << 3)];
                acc[nt] = __builtin_amdgcn_mfma_f32_16x16x32_bf16(afC[ch], bfrag, acc[nt], 0, 0, 0);
            }
        }
        if (k < 8) {
            blendStore((k + 1) & 1);
            if (k < 7) readParams(k + 2);           // ds reads off the issue path
            afC[0] = afN[0];
            afC[1] = afN[1];
        }
    }

    #pragma unroll
    for (int nt = 0; nt < 4; ++nt) {
        #pragma unroll
        for (int reg = 0; reg < 4; ++reg) {
            int oc  = (wv << 4) + (q << 2) + reg;
            int pos = pos0 + (nt << 4) + r;
            float v = acc[nt][reg] + bias[oc];
            out[(size_t)(((b << 6) + oc) << 14) + pos] = fmaxf(v, 0.f);
        }
    }
}

// ---------------------------------------------------------------------------
extern "C" void kernel_launch(void* const* d_in, const int* in_sizes, int n_in,
                              void* d_out, int out_size, void* d_ws, size_t ws_size,
                              hipStream_t stream) {
    const float* data  = (const float*)d_in[0];
    const float* w     = (const float*)d_in[1];
    const float* bias  = (const float*)d_in[2];
    const float* w_off = (const float*)d_in[3];
    const float* b_off = (const float*)d_in[4];
    const float* w_mod = (const float*)d_in[5];
    const float* b_mod = (const float*)d_in[6];
    float* out = (float*)d_out;

    char* ws = (char*)d_ws;
    unsigned short* dataT   = (unsigned short*)(ws + OFF_DATAT);
    float*          offP    = (float*)(ws + OFF_OFFP);
    unsigned short* wpackM  = (unsigned short*)(ws + OFF_WM);
    unsigned short* wpack27 = (unsigned short*)(ws + OFF_W27);
    float*          bias27  = (float*)(ws + OFF_B27);

    prep_k<<<2264, 256, 0, stream>>>(data, dataT, w, w_off, w_mod,
                                     b_off, b_mod, wpackM, wpack27, bias27);
    conv27_k<<<1024, 256, 0, stream>>>(dataT, wpack27, bias27, offP);
    deform_main_k<<<2048, 256, 0, stream>>>(dataT, wpackM, offP, bias, out);
}

// Round 8
// 159.942 us; speedup vs baseline: 1.5690x; 1.0105x over previous
//
#include <hip/hip_runtime.h>
#include <hip/hip_fp16.h>
#include <cstdint>

// ---------------------------------------------------------------------------
// SingleDeformConv on MI355X (gfx950)
// data (8,64,128,128) f32; w (64,64,3,3); b (64); w_off (18,64,3,3); b_off(18);
// w_mod (9,64,3,3); b_mod (9).  out = relu(deform_conv(...)) (8,64,128,128) f32
//
// R7 -> R8: datapath bf16 -> f16. Blend now runs on packed halves via
// v_pk_fma_f16 (4 ops/dword vs 13 with bf16 unpack/fma/pack). MFMA switched
// to 16x16x32_f16 (same layout & rate). Also better precision (f16 mantissa).
// Structure otherwise identical to R7 (pipelined, double-buffered samp,
// 24 B/entry params, 32.2 KB LDS).
// ---------------------------------------------------------------------------

typedef _Float16 half8 __attribute__((ext_vector_type(8)));
typedef __attribute__((ext_vector_type(4))) float floatx4;

// pack two floats -> f16x2 dword (RNE)
__device__ __forceinline__ unsigned int pack2h(float lo, float hi) {
    __half2 h = __floats2half2_rn(lo, hi);
    union { __half2 h; unsigned int u; } cv; cv.h = h;
    return cv.u;
}
// blend one f16x2 dword from 4 corners with broadcast __half2 weights
__device__ __forceinline__ unsigned int blend2h(unsigned int a, unsigned int b,
                                                unsigned int c, unsigned int d,
                                                const __half2* w) {
    union { unsigned int u; __half2 h; } A, B, C, D, O;
    A.u = a; B.u = b; C.u = c; D.u = d;
    __half2 s = __hmul2(A.h, w[0]);
    s = __hfma2(B.h, w[1], s);
    s = __hfma2(C.h, w[2], s);
    s = __hfma2(D.h, w[3], s);
    O.h = s;
    return O.u;
}

// Workspace layout (bytes)
#define OFF_DATAT 0u               // [8][16384][64] f16   = 16777216 B
#define OFF_OFFP  16777216u        // [8][9][3][16384] f32 = 14155776 B (dy,dx,mask)
#define OFF_WM    30932992u        // [64][576] f16        = 73728 B
#define OFF_W27   31006720u        // [32][576] f16        = 36864 B
#define OFF_B27   31043584u        // [32] f32             = 128 B
// total 31043712 B

// ---------------------------------------------------------------------------
// Kernel 1: prep = NCHW f32 -> NHWC f16 transpose (blocks 0..2047)
//           + weight packing / bias27 (blocks 2048..2263)
// ---------------------------------------------------------------------------
__global__ __launch_bounds__(256) void prep_k(const float* __restrict__ x,
                                              unsigned short* __restrict__ xt,
                                              const float* __restrict__ w,
                                              const float* __restrict__ w_off,
                                              const float* __restrict__ w_mod,
                                              const float* __restrict__ b_off,
                                              const float* __restrict__ b_mod,
                                              unsigned short* __restrict__ wpackM,
                                              unsigned short* __restrict__ wpack27,
                                              float* __restrict__ bias27) {
    __shared__ float tile[64][65];
    int blk = blockIdx.x;
    if (blk < 2048) {                              // ---- transpose ----
        int b    = blk >> 8;
        int pos0 = (blk & 255) << 6;
        int lane = threadIdx.x & 63;
        int g    = threadIdx.x >> 6;
        for (int c = g; c < 64; c += 4)
            tile[c][lane] = x[(((b << 6) + c) << 14) + pos0 + lane];
        __syncthreads();
        int c2 = lane & 31;
        for (int i = g; i < 32; i += 4) {
            int pr = (i << 1) + (lane >> 5);
            unsigned int d = pack2h(tile[c2 << 1][pr], tile[(c2 << 1) + 1][pr]);
            *(unsigned int*)&xt[((size_t)((b << 14) + pos0 + pr) << 6) + (c2 << 1)] = d;
        }
        return;
    }
    // ---- weight packing ----
    int t = (blk - 2048) * 256 + threadIdx.x;
    if (t < 64 * 576) {
        int o = t / 576, kk = t % 576;
        int k = kk >> 6, c = kk & 63;
        __half hv = __float2half_rn(w[(o * 64 + c) * 9 + k]);
        wpackM[t] = __half_as_ushort(hv);
        return;
    }
    t -= 64 * 576;
    if (t < 32 * 576) {
        int o = t / 576, kk = t % 576;
        int k = kk >> 6, c = kk & 63;
        float v = 0.f;
        if (o < 18)      v = w_off[(o * 64 + c) * 9 + k];
        else if (o < 27) v = w_mod[((o - 18) * 64 + c) * 9 + k];
        wpack27[t] = __half_as_ushort(__float2half_rn(v));
        if (kk == 0) bias27[o] = (o < 18) ? b_off[o] : (o < 27 ? b_mod[o - 18] : 0.f);
    }
}

// ---------------------------------------------------------------------------
// Kernel 2: offset/mask conv (27 ch, padded to 32) — implicit GEMM, f16 MFMA.
// Block: 256 thr, 2x64 patch, halo [4][66][72] (38 KB), b128 staging.
// ---------------------------------------------------------------------------
__global__ __launch_bounds__(256) void conv27_k(const unsigned short* __restrict__ xt,
                                                const unsigned short* __restrict__ wpack27,
                                                const float* __restrict__ bias27,
                                                float* __restrict__ offP) {
    __shared__ unsigned short tile[4][66][72];
    int blk   = blockIdx.x;                         // 1024 = 8 b * 128 patches
    int b     = blk >> 7;
    int patch = blk & 127;
    int m     = patch >> 1;
    int h     = patch & 1;
    int tid   = threadIdx.x;
    int lane  = tid & 63, wv = tid >> 6;
    int r = lane & 15, q = lane >> 4;

    const unsigned short* xb = xt + ((size_t)b << 20);

    {
        int g = tid >> 3, j = tid & 7;
        #pragma unroll
        for (int rr = 0; rr < 4; ++rr) {
            int sy = (m << 1) + rr - 1;
            #pragma unroll
            for (int ci = 0; ci < 3; ++ci) {
                int col = g + (ci << 5);
                if (col < 66) {
                    int sx = (h << 6) + col - 1;
                    uint4 v = {0u, 0u, 0u, 0u};
                    if (sy >= 0 && sy < 128 && sx >= 0 && sx < 128)
                        v = *(const uint4*)&xb[(size_t)(((sy << 7) + sx) << 6) + (j << 3)];
                    *(uint4*)&tile[rr][col][j << 3] = v;
                }
            }
        }
    }
    __syncthreads();

    floatx4 acc[4] = {};
    #pragma unroll
    for (int k = 0; k < 9; ++k) {
        int ki = k / 3, kj = k % 3;
        #pragma unroll
        for (int ch = 0; ch < 2; ++ch) {
            half8 a0 = *(const half8*)&wpack27[(r)      * 576 + (k << 6) + (ch << 5) + (q << 3)];
            half8 a1 = *(const half8*)&wpack27[(16 + r) * 576 + (k << 6) + (ch << 5) + (q << 3)];
            #pragma unroll
            for (int tr = 0; tr < 2; ++tr) {
                half8 bfrag = *(const half8*)&tile[tr + ki][(wv << 4) + r + kj][(ch << 5) + (q << 3)];
                acc[0 + tr] = __builtin_amdgcn_mfma_f32_16x16x32_f16(a0, bfrag, acc[0 + tr], 0, 0, 0);
                acc[2 + tr] = __builtin_amdgcn_mfma_f32_16x16x32_f16(a1, bfrag, acc[2 + tr], 0, 0, 0);
            }
        }
    }

    #pragma unroll
    for (int s = 0; s < 2; ++s) {
        #pragma unroll
        for (int tr = 0; tr < 2; ++tr) {
            #pragma unroll
            for (int reg = 0; reg < 4; ++reg) {
                int oc = (s << 4) + (q << 2) + reg;
                if (oc >= 27) continue;
                int pos = (((m << 1) + tr) << 7) + (h << 6) + (wv << 4) + r;
                float v = acc[(s << 1) + tr][reg] + bias27[oc];
                int kk, comp;
                if (oc < 18) { kk = oc >> 1; comp = oc & 1; }
                else         { kk = oc - 18; comp = 2; v = 2.f / (1.f + __expf(-v)); }
                offP[(size_t)(((b * 9 + kk) * 3 + comp) << 14) + pos] = v;
            }
        }
    }
}

// ---------------------------------------------------------------------------
// Kernel 3: main deformable conv — R7 pipelined structure, f16 datapath.
// Phase 0: 576 (tap,pos) params: ushort4 corner pos-indices + 4x __half2
// broadcast weights (uint4), 24 B/entry. K-loop: corner b128 loads for tap
// k+1 from register params before the barrier; MFMA(k) from samp[k&1];
// pk_fma_f16 blend(k+1) -> samp[(k+1)&1]. LDS 32.2 KB.
// ---------------------------------------------------------------------------
__global__ __launch_bounds__(256, 5) void deform_main_k(const unsigned short* __restrict__ xt,
                                                        const unsigned short* __restrict__ wpackM,
                                                        const float* __restrict__ offP,
                                                        const float* __restrict__ bias,
                                                        float* __restrict__ out) {
    __shared__ ushort4 pOff[576];                   // 4608 B  corner pos-indices
    __shared__ uint4   pW[576];                     // 9216 B  4x f16x2 weights
    __shared__ unsigned short samp[2][64][72];      // 18432 B B-tile (double buf)
    int blk  = blockIdx.x;                          // 2048 = 8 b * 256
    int b    = blk >> 8;
    int pos0 = (blk & 255) << 6;
    int tid  = threadIdx.x;
    int lane = tid & 63, wv = tid >> 6;
    int r = lane & 15, q = lane >> 4;
    int pg = lane >> 3;                             // position subgroup 0..7
    int j8 = lane & 7;                              // channel chunk (8 f16 = 16B)

    const char* xbb = (const char*)(xt + ((size_t)b << 20));

    // ---- phase 0: params, one thread per (tap,pos) entry ----
    for (int e = tid; e < 576; e += 256) {
        int k = e >> 6, p = e & 63;
        int pos = pos0 + p;
        const float* offk = offP + ((size_t)((b * 9 + k) * 3) << 14);
        float dy = offk[pos];
        float dx = offk[16384 + pos];
        float m  = offk[32768 + pos];
        float py = (float)(pos >> 7) + (float)(k / 3 - 1) + dy;
        float px = (float)(pos & 127) + (float)(k % 3 - 1) + dx;
        float y0f = floorf(py), x0f = floorf(px);
        int y0 = (int)y0f, x0 = (int)x0f;
        float wy1 = py - y0f, wx1 = px - x0f;
        float wy0 = 1.f - wy1, wx0 = 1.f - wx1;
        bool vy0 = (y0 >= 0) && (y0 < 128);
        bool vy1 = (y0 >= -1) && (y0 < 127);
        bool vx0 = (x0 >= 0) && (x0 < 128);
        bool vx1 = (x0 >= -1) && (x0 < 127);
        float w00 = (vy0 && vx0) ? m * wy0 * wx0 : 0.f;
        float w01 = (vy0 && vx1) ? m * wy0 * wx1 : 0.f;
        float w10 = (vy1 && vx0) ? m * wy1 * wx0 : 0.f;
        float w11 = (vy1 && vx1) ? m * wy1 * wx1 : 0.f;
        int y0c = min(max(y0, 0), 127), y1c = min(max(y0 + 1, 0), 127);
        int x0c = min(max(x0, 0), 127), x1c = min(max(x0 + 1, 0), 127);
        ushort4 io;
        io.x = (unsigned short)((y0c << 7) + x0c);
        io.y = (unsigned short)((y0c << 7) + x1c);
        io.z = (unsigned short)((y1c << 7) + x0c);
        io.w = (unsigned short)((y1c << 7) + x1c);
        pOff[e] = io;
        union { uint4 u; __half2 h[4]; } pw;
        pw.h[0] = __float2half2_rn(w00);
        pw.h[1] = __float2half2_rn(w01);
        pw.h[2] = __float2half2_rn(w10);
        pw.h[3] = __float2half2_rn(w11);
        pW[e] = pw.u;
    }
    __syncthreads();                                // pOff/pW ready

    floatx4 acc[4] = {};
    const char* xp = xbb + (j8 << 4);               // per-lane channel-chunk base
    const unsigned short* wrow = wpackM + ((wv << 4) + r) * 576 + (q << 3);

    uint4   c00[2], c01[2], c10[2], c11[2];         // prefetched corners
    ushort4 pio[2];                                 // params for next issue
    uint4   pcw[2];
    uint4   cw[2];                                  // weights matching corners
    half8   afC[2], afN[2];                         // A-frags, current / next

    auto readParams = [&](int k) {
        #pragma unroll
        for (int i = 0; i < 2; ++i) {
            int e  = (k << 6) + (wv << 4) + (i << 3) + pg;
            pio[i] = pOff[e];
            pcw[i] = pW[e];
        }
    };
    auto issue = [&]() {                            // fire globals from registers
        #pragma unroll
        for (int i = 0; i < 2; ++i) {
            cw[i]  = pcw[i];
            c00[i] = *(const uint4*)(xp + ((int)pio[i].x << 7));
            c01[i] = *(const uint4*)(xp + ((int)pio[i].y << 7));
            c10[i] = *(const uint4*)(xp + ((int)pio[i].z << 7));
            c11[i] = *(const uint4*)(xp + ((int)pio[i].w << 7));
        }
    };
    auto blendStore = [&](int buf) {
        #pragma unroll
        for (int i = 0; i < 2; ++i) {
            int p = (wv << 4) + (i << 3) + pg;
            union { uint4 u; __half2 h[4]; } W; W.u = cw[i];
            uint4 o4;
            o4.x = blend2h(c00[i].x, c01[i].x, c10[i].x, c11[i].x, W.h);
            o4.y = blend2h(c00[i].y, c01[i].y, c10[i].y, c11[i].y, W.h);
            o4.z = blend2h(c00[i].z, c01[i].z, c10[i].z, c11[i].z, W.h);
            o4.w = blend2h(c00[i].w, c01[i].w, c10[i].w, c11[i].w, W.h);
            *(uint4*)&samp[buf][p][j8 << 3] = o4;
        }
    };

    // prologue: tap 0 through the pipe; params for tap 1 staged in registers
    readParams(0);
    issue();
    afC[0] = *(const half8*)&wrow[0];
    afC[1] = *(const half8*)&wrow[32];
    blendStore(0);
    readParams(1);

    for (int k = 0; k < 9; ++k) {
        if (k < 8) {
            issue();                                // tap k+1 globals in flight
            afN[0] = *(const half8*)&wrow[((k + 1) << 6)];
            afN[1] = *(const half8*)&wrow[((k + 1) << 6) + 32];
        }
        __syncthreads();                            // samp[k&1] complete block-wide
        #pragma unroll
        for (int ch = 0; ch < 2; ++ch) {
            #pragma unroll
            for (int nt = 0; nt < 4; ++nt) {
                half8 bfrag = *(const half8*)&samp[k & 1][(nt << 4) + r][(ch << 5) + (q << 3)];
                acc[nt] = __builtin_amdgcn_mfma_f32_16x16x32_f16(afC[ch], bfrag, acc[nt], 0, 0, 0);
            }
        }
        if (k < 8) {
            blendStore((k + 1) & 1);
            if (k < 7) readParams(k + 2);           // ds reads off the issue path
            afC[0] = afN[0];
            afC[1] = afN[1];
        }
    }

    #pragma unroll
    for (int nt = 0; nt < 4; ++nt) {
        #pragma unroll
        for (int reg = 0; reg < 4; ++reg) {
            int oc  = (wv << 4) + (q << 2) + reg;
            int pos = pos0 + (nt << 4) + r;
            float v = acc[nt][reg] + bias[oc];
            out[(size_t)(((b << 6) + oc) << 14) + pos] = fmaxf(v, 0.f);
        }
    }
}

// ---------------------------------------------------------------------------
extern "C" void kernel_launch(void* const* d_in, const int* in_sizes, int n_in,
                              void* d_out, int out_size, void* d_ws, size_t ws_size,
                              hipStream_t stream) {
    const float* data  = (const float*)d_in[0];
    const float* w     = (const float*)d_in[1];
    const float* bias  = (const float*)d_in[2];
    const float* w_off = (const float*)d_in[3];
    const float* b_off = (const float*)d_in[4];
    const float* w_mod = (const float*)d_in[5];
    const float* b_mod = (const float*)d_in[6];
    float* out = (float*)d_out;

    char* ws = (char*)d_ws;
    unsigned short* dataT   = (unsigned short*)(ws + OFF_DATAT);
    float*          offP    = (float*)(ws + OFF_OFFP);
    unsigned short* wpackM  = (unsigned short*)(ws + OFF_WM);
    unsigned short* wpack27 = (unsigned short*)(ws + OFF_W27);
    float*          bias27  = (float*)(ws + OFF_B27);

    prep_k<<<2264, 256, 0, stream>>>(data, dataT, w, w_off, w_mod,
                                     b_off, b_mod, wpackM, wpack27, bias27);
    conv27_k<<<1024, 256, 0, stream>>>(dataT, wpack27, bias27, offP);
    deform_main_k<<<2048, 256, 0, stream>>>(dataT, wpackM, offP, bias, out);
}

// Round 11
// 157.994 us; speedup vs baseline: 1.5884x; 1.0123x over previous
//
#include <hip/hip_runtime.h>
#include <hip/hip_fp16.h>
#include <cstdint>

// ---------------------------------------------------------------------------
// SingleDeformConv on MI355X (gfx950)
// data (8,64,128,128) f32; w (64,64,3,3); b (64); w_off (18,64,3,3); b_off(18);
// w_mod (9,64,3,3); b_mod (9).  out = relu(deform_conv(...)) (8,64,128,128) f32
//
// R10 -> R11: R9's two-tap corner pipeline, de-risked. The k-loop is now
// FULLY UNROLLED so all register-array set selectors (k&1 etc.) are
// compile-time constants — no dynamic private-array indexing, no scratch.
// launch_bounds relaxed to (256,3) so the ~140-VGPR live set doesn't spill.
// (R9/R10 "container failed twice" x2 suspected to be codegen pathology from
// runtime-indexed register arrays in the non-unrolled loop.)
// ---------------------------------------------------------------------------

typedef _Float16 half8 __attribute__((ext_vector_type(8)));
typedef __attribute__((ext_vector_type(4))) float floatx4;

// pack two floats -> f16x2 dword (RNE)
__device__ __forceinline__ unsigned int pack2h(float lo, float hi) {
    __half2 h = __floats2half2_rn(lo, hi);
    union { __half2 h; unsigned int u; } cv; cv.h = h;
    return cv.u;
}
// blend one f16x2 dword from 4 corners with broadcast __half2 weights
__device__ __forceinline__ unsigned int blend2h(unsigned int a, unsigned int b,
                                                unsigned int c, unsigned int d,
                                                const __half2* w) {
    union { unsigned int u; __half2 h; } A, B, C, D, O;
    A.u = a; B.u = b; C.u = c; D.u = d;
    __half2 s = __hmul2(A.h, w[0]);
    s = __hfma2(B.h, w[1], s);
    s = __hfma2(C.h, w[2], s);
    s = __hfma2(D.h, w[3], s);
    O.h = s;
    return O.u;
}

// Workspace layout (bytes)
#define OFF_DATAT 0u               // [8][16384][64] f16   = 16777216 B
#define OFF_OFFP  16777216u        // [8][9][3][16384] f32 = 14155776 B (dy,dx,mask)
#define OFF_WM    30932992u        // [64][576] f16        = 73728 B
#define OFF_W27   31006720u        // [32][576] f16        = 36864 B
#define OFF_B27   31043584u        // [32] f32             = 128 B
// total 31043712 B

// ---------------------------------------------------------------------------
// Kernel 1: prep = NCHW f32 -> NHWC f16 transpose (blocks 0..2047)
//           + weight packing / bias27 (blocks 2048..2263)
// ---------------------------------------------------------------------------
__global__ __launch_bounds__(256) void prep_k(const float* __restrict__ x,
                                              unsigned short* __restrict__ xt,
                                              const float* __restrict__ w,
                                              const float* __restrict__ w_off,
                                              const float* __restrict__ w_mod,
                                              const float* __restrict__ b_off,
                                              const float* __restrict__ b_mod,
                                              unsigned short* __restrict__ wpackM,
                                              unsigned short* __restrict__ wpack27,
                                              float* __restrict__ bias27) {
    __shared__ float tile[64][65];
    int blk = blockIdx.x;
    if (blk < 2048) {                              // ---- transpose ----
        int b    = blk >> 8;
        int pos0 = (blk & 255) << 6;
        int lane = threadIdx.x & 63;
        int g    = threadIdx.x >> 6;
        for (int c = g; c < 64; c += 4)
            tile[c][lane] = x[(((b << 6) + c) << 14) + pos0 + lane];
        __syncthreads();
        int c2 = lane & 31;
        for (int i = g; i < 32; i += 4) {
            int pr = (i << 1) + (lane >> 5);
            unsigned int d = pack2h(tile[c2 << 1][pr], tile[(c2 << 1) + 1][pr]);
            *(unsigned int*)&xt[((size_t)((b << 14) + pos0 + pr) << 6) + (c2 << 1)] = d;
        }
        return;
    }
    // ---- weight packing ----
    int t = (blk - 2048) * 256 + threadIdx.x;
    if (t < 64 * 576) {
        int o = t / 576, kk = t % 576;
        int k = kk >> 6, c = kk & 63;
        wpackM[t] = __half_as_ushort(__float2half_rn(w[(o * 64 + c) * 9 + k]));
        return;
    }
    t -= 64 * 576;
    if (t < 32 * 576) {
        int o = t / 576, kk = t % 576;
        int k = kk >> 6, c = kk & 63;
        float v = 0.f;
        if (o < 18)      v = w_off[(o * 64 + c) * 9 + k];
        else if (o < 27) v = w_mod[((o - 18) * 64 + c) * 9 + k];
        wpack27[t] = __half_as_ushort(__float2half_rn(v));
        if (kk == 0) bias27[o] = (o < 18) ? b_off[o] : (o < 27 ? b_mod[o - 18] : 0.f);
    }
}

// ---------------------------------------------------------------------------
// Kernel 2: offset/mask conv (27 ch, padded to 32) — implicit GEMM, f16 MFMA.
// Block: 256 thr, 2x64 patch, halo [4][66][72] (38 KB), b128 staging.
// ---------------------------------------------------------------------------
__global__ __launch_bounds__(256) void conv27_k(const unsigned short* __restrict__ xt,
                                                const unsigned short* __restrict__ wpack27,
                                                const float* __restrict__ bias27,
                                                float* __restrict__ offP) {
    __shared__ unsigned short tile[4][66][72];
    int blk   = blockIdx.x;                         // 1024 = 8 b * 128 patches
    int b     = blk >> 7;
    int patch = blk & 127;
    int m     = patch >> 1;
    int h     = patch & 1;
    int tid   = threadIdx.x;
    int lane  = tid & 63, wv = tid >> 6;
    int r = lane & 15, q = lane >> 4;

    const unsigned short* xb = xt + ((size_t)b << 20);

    {
        int g = tid >> 3, j = tid & 7;
        #pragma unroll
        for (int rr = 0; rr < 4; ++rr) {
            int sy = (m << 1) + rr - 1;
            #pragma unroll
            for (int ci = 0; ci < 3; ++ci) {
                int col = g + (ci << 5);
                if (col < 66) {
                    int sx = (h << 6) + col - 1;
                    uint4 v = {0u, 0u, 0u, 0u};
                    if (sy >= 0 && sy < 128 && sx >= 0 && sx < 128)
                        v = *(const uint4*)&xb[(size_t)(((sy << 7) + sx) << 6) + (j << 3)];
                    *(uint4*)&tile[rr][col][j << 3] = v;
                }
            }
        }
    }
    __syncthreads();

    floatx4 acc[4] = {};
    #pragma unroll
    for (int k = 0; k < 9; ++k) {
        int ki = k / 3, kj = k % 3;
        #pragma unroll
        for (int ch = 0; ch < 2; ++ch) {
            half8 a0 = *(const half8*)&wpack27[(r)      * 576 + (k << 6) + (ch << 5) + (q << 3)];
            half8 a1 = *(const half8*)&wpack27[(16 + r) * 576 + (k << 6) + (ch << 5) + (q << 3)];
            #pragma unroll
            for (int tr = 0; tr < 2; ++tr) {
                half8 bfrag = *(const half8*)&tile[tr + ki][(wv << 4) + r + kj][(ch << 5) + (q << 3)];
                acc[0 + tr] = __builtin_amdgcn_mfma_f32_16x16x32_f16(a0, bfrag, acc[0 + tr], 0, 0, 0);
                acc[2 + tr] = __builtin_amdgcn_mfma_f32_16x16x32_f16(a1, bfrag, acc[2 + tr], 0, 0, 0);
            }
        }
    }

    #pragma unroll
    for (int s = 0; s < 2; ++s) {
        #pragma unroll
        for (int tr = 0; tr < 2; ++tr) {
            #pragma unroll
            for (int reg = 0; reg < 4; ++reg) {
                int oc = (s << 4) + (q << 2) + reg;
                if (oc >= 27) continue;
                int pos = (((m << 1) + tr) << 7) + (h << 6) + (wv << 4) + r;
                float v = acc[(s << 1) + tr][reg] + bias27[oc];
                int kk, comp;
                if (oc < 18) { kk = oc >> 1; comp = oc & 1; }
                else         { kk = oc - 18; comp = 2; v = 2.f / (1.f + __expf(-v)); }
                offP[(size_t)(((b * 9 + kk) * 3 + comp) << 14) + pos] = v;
            }
        }
    }
}

// ---------------------------------------------------------------------------
// Kernel 3: main deformable conv — two-tap pipelined f16 datapath,
// FULLY UNROLLED k-loop (all set selectors compile-time).
// Body k: issue corners for tap k+2 into set (k&1); barrier; MFMA(k) from
// samp[k&1]; blendStore tap k+1 from set ((k+1)&1) -> samp[(k+1)&1];
// readParams(k+3). ~2 barrier+MFMA phases of corner-load latency slack.
// ---------------------------------------------------------------------------
__global__ __launch_bounds__(256, 3) void deform_main_k(const unsigned short* __restrict__ xt,
                                                        const unsigned short* __restrict__ wpackM,
                                                        const float* __restrict__ offP,
                                                        const float* __restrict__ bias,
                                                        float* __restrict__ out) {
    __shared__ ushort4 pOff[576];                   // 4608 B  corner pos-indices
    __shared__ uint4   pW[576];                     // 9216 B  4x f16x2 weights
    __shared__ unsigned short samp[2][64][72];      // 18432 B B-tile (double buf)
    int blk  = blockIdx.x;                          // 2048 = 8 b * 256
    int b    = blk >> 8;
    int pos0 = (blk & 255) << 6;
    int tid  = threadIdx.x;
    int lane = tid & 63, wv = tid >> 6;
    int r = lane & 15, q = lane >> 4;
    int pg = lane >> 3;                             // position subgroup 0..7
    int j8 = lane & 7;                              // channel chunk (8 f16 = 16B)

    const char* xbb = (const char*)(xt + ((size_t)b << 20));

    // ---- phase 0: params, one thread per (tap,pos) entry ----
    for (int e = tid; e < 576; e += 256) {
        int k = e >> 6, p = e & 63;
        int pos = pos0 + p;
        const float* offk = offP + ((size_t)((b * 9 + k) * 3) << 14);
        float dy = offk[pos];
        float dx = offk[16384 + pos];
        float m  = offk[32768 + pos];
        float py = (float)(pos >> 7) + (float)(k / 3 - 1) + dy;
        float px = (float)(pos & 127) + (float)(k % 3 - 1) + dx;
        float y0f = floorf(py), x0f = floorf(px);
        int y0 = (int)y0f, x0 = (int)x0f;
        float wy1 = py - y0f, wx1 = px - x0f;
        float wy0 = 1.f - wy1, wx0 = 1.f - wx1;
        bool vy0 = (y0 >= 0) && (y0 < 128);
        bool vy1 = (y0 >= -1) && (y0 < 127);
        bool vx0 = (x0 >= 0) && (x0 < 128);
        bool vx1 = (x0 >= -1) && (x0 < 127);
        float w00 = (vy0 && vx0) ? m * wy0 * wx0 : 0.f;
        float w01 = (vy0 && vx1) ? m * wy0 * wx1 : 0.f;
        float w10 = (vy1 && vx0) ? m * wy1 * wx0 : 0.f;
        float w11 = (vy1 && vx1) ? m * wy1 * wx1 : 0.f;
        int y0c = min(max(y0, 0), 127), y1c = min(max(y0 + 1, 0), 127);
        int x0c = min(max(x0, 0), 127), x1c = min(max(x0 + 1, 0), 127);
        ushort4 io;
        io.x = (unsigned short)((y0c << 7) + x0c);
        io.y = (unsigned short)((y0c << 7) + x1c);
        io.z = (unsigned short)((y1c << 7) + x0c);
        io.w = (unsigned short)((y1c << 7) + x1c);
        pOff[e] = io;
        union { uint4 u; __half2 h[4]; } pw;
        pw.h[0] = __float2half2_rn(w00);
        pw.h[1] = __float2half2_rn(w01);
        pw.h[2] = __float2half2_rn(w10);
        pw.h[3] = __float2half2_rn(w11);
        pW[e] = pw.u;
    }
    __syncthreads();                                // pOff/pW ready

    floatx4 acc[4] = {};
    const char* xp = xbb + (j8 << 4);               // per-lane channel-chunk base
    const unsigned short* wrow = wpackM + ((wv << 4) + r) * 576 + (q << 3);

    // two corner register sets (set = tap & 1) — only ever indexed by
    // compile-time constants (k-loop fully unrolled below).
    uint4   c00[2][2], c01[2][2], c10[2][2], c11[2][2];  // [set][i]
    uint4   cwS[2][2];                              // weights per set
    ushort4 nio[2];                                 // staged params (next issue)
    uint4   ncw[2];
    half8   afC[2], afN[2];                         // A-frags, current / next

    auto readParams = [&](int k) {
        #pragma unroll
        for (int i = 0; i < 2; ++i) {
            int e  = (k << 6) + (wv << 4) + (i << 3) + pg;
            nio[i] = pOff[e];
            ncw[i] = pW[e];
        }
    };
    auto issueInto = [&](int s) {                   // s is compile-time at all call sites
        #pragma unroll
        for (int i = 0; i < 2; ++i) {
            cwS[s][i] = ncw[i];
            c00[s][i] = *(const uint4*)(xp + ((int)nio[i].x << 7));
            c01[s][i] = *(const uint4*)(xp + ((int)nio[i].y << 7));
            c10[s][i] = *(const uint4*)(xp + ((int)nio[i].z << 7));
            c11[s][i] = *(const uint4*)(xp + ((int)nio[i].w << 7));
        }
    };
    auto blendStore = [&](int s, int buf) {         // s, buf compile-time
        #pragma unroll
        for (int i = 0; i < 2; ++i) {
            int p = (wv << 4) + (i << 3) + pg;
            union { uint4 u; __half2 h[4]; } W; W.u = cwS[s][i];
            uint4 o4;
            o4.x = blend2h(c00[s][i].x, c01[s][i].x, c10[s][i].x, c11[s][i].x, W.h);
            o4.y = blend2h(c00[s][i].y, c01[s][i].y, c10[s][i].y, c11[s][i].y, W.h);
            o4.z = blend2h(c00[s][i].z, c01[s][i].z, c10[s][i].z, c11[s][i].z, W.h);
            o4.w = blend2h(c00[s][i].w, c01[s][i].w, c10[s][i].w, c11[s][i].w, W.h);
            *(uint4*)&samp[buf][p][j8 << 3] = o4;
        }
    };

    // prologue: taps 0 and 1 into the pipe; params(2) staged
    readParams(0); issueInto(0);
    readParams(1); issueInto(1);
    afC[0] = *(const half8*)&wrow[0];
    afC[1] = *(const half8*)&wrow[32];
    blendStore(0, 0);                               // blend tap0 -> samp[0]
    readParams(2);

    #pragma unroll
    for (int k = 0; k < 9; ++k) {
        if (k <= 6) issueInto(k & 1);               // corners for tap k+2
        if (k < 8) {
            afN[0] = *(const half8*)&wrow[((k + 1) << 6)];
            afN[1] = *(const half8*)&wrow[((k + 1) << 6) + 32];
        }
        __syncthreads();                            // samp[k&1] complete block-wide
        #pragma unroll
        for (int ch = 0; ch < 2; ++ch) {
            #pragma unroll
            for (int nt = 0; nt < 4; ++nt) {
                half8 bfrag = *(const half8*)&samp[k & 1][(nt << 4) + r][(ch << 5) + (q << 3)];
                acc[nt] = __builtin_amdgcn_mfma_f32_16x16x32_f16(afC[ch], bfrag, acc[nt], 0, 0, 0);
            }
        }
        if (k < 8) {
            blendStore((k + 1) & 1, (k + 1) & 1);   // corners issued at body k-1
            if (k <= 5) readParams(k + 3);          // params for issue at body k+1
            afC[0] = afN[0];
            afC[1] = afN[1];
        }
    }

    #pragma unroll
    for (int nt = 0; nt < 4; ++nt) {
        #pragma unroll
        for (int reg = 0; reg < 4; ++reg) {
            int oc  = (wv << 4) + (q << 2) + reg;
            int pos = pos0 + (nt << 4) + r;
            float v = acc[nt][reg] + bias[oc];
            out[(size_t)(((b << 6) + oc) << 14) + pos] = fmaxf(v, 0.f);
        }
    }
}

// ---------------------------------------------------------------------------
extern "C" void kernel_launch(void* const* d_in, const int* in_sizes, int n_in,
                              void* d_out, int out_size, void* d_ws, size_t ws_size,
                              hipStream_t stream) {
    const float* data  = (const float*)d_in[0];
    const float* w     = (const float*)d_in[1];
    const float* bias  = (const float*)d_in[2];
    const float* w_off = (const float*)d_in[3];
    const float* b_off = (const float*)d_in[4];
    const float* w_mod = (const float*)d_in[5];
    const float* b_mod = (const float*)d_in[6];
    float* out = (float*)d_out;

    char* ws = (char*)d_ws;
    unsigned short* dataT   = (unsigned short*)(ws + OFF_DATAT);
    float*          offP    = (float*)(ws + OFF_OFFP);
    unsigned short* wpackM  = (unsigned short*)(ws + OFF_WM);
    unsigned short* wpack27 = (unsigned short*)(ws + OFF_W27);
    float*          bias27  = (float*)(ws + OFF_B27);

    prep_k<<<2264, 256, 0, stream>>>(data, dataT, w, w_off, w_mod,
                                     b_off, b_mod, wpackM, wpack27, bias27);
    conv27_k<<<1024, 256, 0, stream>>>(dataT, wpack27, bias27, offP);
    deform_main_k<<<2048, 256, 0, stream>>>(dataT, wpackM, offP, bias, out);
}